// Round 15
// baseline (362.771 us; speedup 1.0000x reference)
//
#include <hip/hip_runtime.h>
#include <cmath>

typedef _Float16 f16;
typedef _Float16 f16x8 __attribute__((ext_vector_type(8)));
typedef float f32x4 __attribute__((ext_vector_type(4)));
typedef unsigned int u32x4 __attribute__((ext_vector_type(4)));

#define B 64
#define S 80
#define KC 32
#define EDIM 256
#define HDIM 512
#define G3 1536
#define LDIM 128

// persistent-GRU geometry (R11 core — best measured: 205us, 2.56us/step)
#define NG 8     // groups (grid(8,32): linear%8 == g -> one XCD per group)
#define PG 8     // patients per group
#define NJ 32    // blocks per group
#define CPB 16   // h-cols per block

// sync area layout (u32 units)
#define OFF_PCNT  (NG * NJ * 64)
#define OFF_XCD   (OFF_PCNT + NG * 64)
#define OFF_TEST  (OFF_XCD + NG * NJ)
#define OFF_FAIL  (OFF_TEST + NG * NJ * 64)
#define SYNC_TOTAL (OFF_FAIL + NG)

// ---------------------------------------------------------------------------
__device__ __forceinline__ unsigned int ld_u32c(const unsigned int* p, bool l2) {
    unsigned int v;
    if (l2) {
        asm volatile("global_load_dword %0, %1, off sc0\n\ts_waitcnt vmcnt(0)"
                     : "=v"(v) : "v"(p) : "memory");
    } else {
        v = __hip_atomic_load(p, __ATOMIC_RELAXED, __HIP_MEMORY_SCOPE_AGENT);
    }
    return v;
}
__device__ __forceinline__ void st_u32c(unsigned int* p, unsigned int v, bool l2) {
    if (l2) {
        asm volatile("global_store_dword %0, %1, off sc0" :: "v"(p), "v"(v) : "memory");
    } else {
        __hip_atomic_store(p, v, __ATOMIC_RELAXED, __HIP_MEMORY_SCOPE_AGENT);
    }
}

// ---------------------------------------------------------------------------
// K1: multi-hot embedding + tanh -> f16.
__global__ __launch_bounds__(256) void emb_kernel(const int* __restrict__ seq,
                                                  const float* __restrict__ Ew,
                                                  unsigned short* __restrict__ emb16) {
    int bs = blockIdx.x;
    __shared__ int codes[KC];
    __shared__ int valid[KC];
    int tid = threadIdx.x;
    if (tid < KC) codes[tid] = seq[bs * KC + tid];
    __syncthreads();
    if (tid < KC) {
        int c = codes[tid];
        int v = (c != 0);
        for (int i = 0; i < tid; ++i)
            if (codes[i] == c) v = 0;
        valid[tid] = v;
    }
    __syncthreads();
    float acc = 0.f;
    for (int j = 0; j < KC; ++j) {
        if (valid[j]) acc += Ew[codes[j] * EDIM + tid];
    }
    emb16[bs * EDIM + tid] = __builtin_bit_cast(unsigned short, (f16)tanhf(acc));
}

// ---------------------------------------------------------------------------
// K2: Gi16 = emb16 @ Wi16^T + bi via MFMA f16 (verified).
__global__ __launch_bounds__(256) void gi_gemm16(
        const unsigned short* __restrict__ wi16,
        const unsigned short* __restrict__ emb16,
        const float* __restrict__ bi,
        unsigned short* __restrict__ gi16) {
    __shared__ __align__(16) f16 At[64][256];
    __shared__ __align__(16) f16 Bt[64][256];
    const int m0 = blockIdx.x * 64;   // visits
    const int n0 = blockIdx.y * 64;   // gates
    const int tid = threadIdx.x;
    #pragma unroll
    for (int i = 0; i < 8; ++i) {
        int ci = tid + i * 256;
        int row = ci >> 5, c = ci & 31;
        int sc = c ^ (row & 7);
        *(f32x4*)&At[row][sc * 8] =
            *(const f32x4*)(wi16 + (size_t)(n0 + row) * EDIM + c * 8);
        *(f32x4*)&Bt[row][sc * 8] =
            *(const f32x4*)(emb16 + (size_t)(m0 + row) * EDIM + c * 8);
    }
    __syncthreads();
    const int wv = tid >> 6, ln = tid & 63;
    const int lr = ln & 15, hi = ln >> 4;
    const int arow = wv * 16 + lr;
    f32x4 acc[4] = {};
    #pragma unroll
    for (int ks = 0; ks < 8; ++ks) {
        int ca = (ks * 4 + hi) ^ (arow & 7);
        f32x4 av = *(const f32x4*)&At[arow][ca * 8];
        #pragma unroll
        for (int vt = 0; vt < 4; ++vt) {
            int brow = vt * 16 + lr;
            int cb = (ks * 4 + hi) ^ (brow & 7);
            f32x4 bv = *(const f32x4*)&Bt[brow][cb * 8];
            acc[vt] = __builtin_amdgcn_mfma_f32_16x16x32_f16(
                __builtin_bit_cast(f16x8, av), __builtin_bit_cast(f16x8, bv),
                acc[vt], 0, 0, 0);
        }
    }
    const int gate0 = n0 + wv * 16 + hi * 4;
    float4 bv4 = *(const float4*)(bi + gate0);
    #pragma unroll
    for (int vt = 0; vt < 4; ++vt) {
        int vis = m0 + vt * 16 + lr;
        union { unsigned short u[4]; unsigned long long ll; } pk;
        pk.u[0] = __builtin_bit_cast(unsigned short, (f16)(acc[vt][0] + bv4.x));
        pk.u[1] = __builtin_bit_cast(unsigned short, (f16)(acc[vt][1] + bv4.y));
        pk.u[2] = __builtin_bit_cast(unsigned short, (f16)(acc[vt][2] + bv4.z));
        pk.u[3] = __builtin_bit_cast(unsigned short, (f16)(acc[vt][3] + bv4.w));
        *(unsigned long long*)(gi16 + (size_t)vis * G3 + gate0) = pk.ll;
    }
}

// ---------------------------------------------------------------------------
// K3: init — zero h buffers + sync, convert Wi/Wh -> f16, rank.
__global__ __launch_bounds__(256) void init_kernel(const int* __restrict__ len,
                                                   const float* __restrict__ Wi,
                                                   const float* __restrict__ Wh,
                                                   int* __restrict__ rank,
                                                   unsigned int* __restrict__ sync,
                                                   unsigned int* __restrict__ hz,
                                                   unsigned short* __restrict__ wi16,
                                                   unsigned short* __restrict__ wh16) {
    int idx = blockIdx.x * 256 + threadIdx.x;       // 128*256 = 32768
    if (idx < 16384) { hz[idx] = 0u; hz[16384 + idx] = 0u; }   // h0f+h1f
    for (int o = idx; o < SYNC_TOTAL; o += 32768) sync[o] = 0u;
    for (int o = idx; o < G3 * EDIM; o += 32768)
        wi16[o] = __builtin_bit_cast(unsigned short, (f16)Wi[o]);
    for (int o = idx; o < G3 * HDIM; o += 32768)
        wh16[o] = __builtin_bit_cast(unsigned short, (f16)Wh[o]);
    if (blockIdx.x == 0 && threadIdx.x < B) {
        int t = threadIdx.x;
        int lb = len[t];
        int r = 0;
        for (int i = 0; i < B; ++i) {
            int li = len[i];
            r += (li > lb) || (li == lb && i < t);
        }
        rank[t] = r;
    }
}

// ---------------------------------------------------------------------------
// K4: persistent MFMA GRU — R11 core (best: 205us) + SOFTWARE-PIPELINED
// weight reload: af (48KB/block, which the allocator refuses to keep
// resident -> VGPR=60 in R11, reloaded from L2 serially inside the MFMA
// phase) is explicitly reloaded for step t+1 in step t's tail, AFTER the
// flag publish and overlapping the poll window; B3's implicit vmcnt drain
// completes them.  An opaque-pointer pin each iteration prevents CSE /
// hoisting.  Values are constant, so the reload is trivially correct.
__global__ __launch_bounds__(256, 1) void gru_persist(
        const unsigned short* __restrict__ gi16,
        const unsigned short* __restrict__ wh16,
        const float* __restrict__ bh, const int* __restrict__ len,
        unsigned short* __restrict__ h0f, unsigned short* __restrict__ h1f,
        unsigned short* __restrict__ hout,
        unsigned int* __restrict__ sync) {
    const int g     = blockIdx.x;          // 0..NG-1
    const int slice = blockIdx.y;          // 0..NJ-1
    const int tid   = threadIdx.x;
    const int wv    = tid >> 6;
    const int ln    = tid & 63;
    const int c0    = slice * CPB;

    __shared__ __align__(16) f16 hsb[64][16][8];   // [k8][pat(8+8 pad)][8]
    __shared__ float ghl[3][16][16];
    __shared__ f16 hst[PG][CPB];                   // h-store staging
    __shared__ unsigned int ids_sh[NJ];
    __shared__ unsigned int fail_sh;

    // zero pad-patient rows once (stay zero)
    for (int c = tid; c < 64 * 8; c += 256)
        *(float4*)&hsb[c >> 3][8 + (c & 7)][0] = make_float4(0.f, 0.f, 0.f, 0.f);

    // ---- A-operand source pointer + initial load (per wave, wv<3)
    const unsigned short* wrow =
        wh16 + (size_t)(min(wv, 2) * HDIM + c0 + (ln & 15)) * HDIM + (ln >> 4) * 8;
    f32x4 af[16];
    if (wv < 3) {
        #pragma unroll
        for (int ks = 0; ks < 16; ++ks)
            af[ks] = *(const f32x4*)(wrow + ks * 32);
    } else {
        #pragma unroll
        for (int ks = 0; ks < 16; ++ks) af[ks] = (f32x4){0.f, 0.f, 0.f, 0.f};
    }

    // ---- sync pointers
    unsigned int* gflags = sync + (size_t)(g * NJ) * 64;
    unsigned int* pcnt   = sync + OFF_PCNT + g * 64;
    unsigned int* xcdrow = sync + OFF_XCD + g * NJ;
    unsigned int* town   = sync + OFF_TEST + (g * NJ + slice) * 64;
    unsigned int* tpeer  = sync + OFF_TEST + (g * NJ + ((slice + 1) & (NJ - 1))) * 64;
    unsigned int* failw  = sync + OFF_FAIL + g;

    auto l3bar = [&](unsigned int target) {
        if (tid == 0) {
            asm volatile("s_waitcnt vmcnt(0)" ::: "memory");
            __hip_atomic_fetch_add(pcnt, 1u, __ATOMIC_RELAXED, __HIP_MEMORY_SCOPE_AGENT);
            while (__hip_atomic_load(pcnt, __ATOMIC_RELAXED, __HIP_MEMORY_SCOPE_AGENT) < target)
                __builtin_amdgcn_s_sleep(1);
        }
        __syncthreads();
    };

    // ---- XCD identity + sc0 coherence probe (R6 recipe, proven)
    unsigned int myxcc;
    asm volatile("s_getreg_b32 %0, hwreg(HW_REG_XCC_ID)" : "=s"(myxcc));
    myxcc &= 0xFu;
    if (tid == 0)
        __hip_atomic_store(xcdrow + slice, myxcc, __ATOMIC_RELAXED, __HIP_MEMORY_SCOPE_AGENT);
    l3bar(NJ);
    if (tid < NJ)
        ids_sh[tid] = __hip_atomic_load(xcdrow + tid, __ATOMIC_RELAXED, __HIP_MEMORY_SCOPE_AGENT);
    __syncthreads();
    bool same_xcd = true;
    #pragma unroll
    for (int i = 1; i < NJ; ++i) same_xcd &= (ids_sh[i] == ids_sh[0]);

    bool l2m = false;
    if (same_xcd) {
        const unsigned int M1 = 0xA5A50000u + (unsigned)slice;
        const unsigned int M2 = 0x5A5A0000u + (unsigned)slice;
        const unsigned int P1 = 0xA5A50000u + (unsigned)((slice + 1) & (NJ - 1));
        const unsigned int P2 = 0x5A5A0000u + (unsigned)((slice + 1) & (NJ - 1));
        unsigned int r1 = 0, r2 = 0;
        if (tid == 0) st_u32c(town, M1, true);
        l3bar(2 * NJ);
        if (tid == 0) r1 = ld_u32c(tpeer, true);
        l3bar(3 * NJ);
        if (tid == 0) st_u32c(town, M2, true);
        l3bar(4 * NJ);
        if (tid == 0) {
            r2 = ld_u32c(tpeer, true);
            if (r1 != P1 || r2 != P2)
                __hip_atomic_fetch_or(failw, 1u, __ATOMIC_RELAXED, __HIP_MEMORY_SCOPE_AGENT);
        }
        l3bar(5 * NJ);
        if (tid == 0)
            fail_sh = __hip_atomic_load(failw, __ATOMIC_RELAXED, __HIP_MEMORY_SCOPE_AGENT);
        __syncthreads();
        l2m = (fail_sh == 0u);
    }

    // ---- per-thread statics (tid<128: one (pat, col) each)
    const int pat  = tid & 7;
    const int hc   = tid >> 3;
    const int colg = c0 + hc;
    const int fb   = g * PG + pat;
    float bhr = 0.f, bhz = 0.f, bhn = 0.f;
    const unsigned short* gi_b = gi16;
    int flen = 0;
    if (tid < 128) {
        bhr = bh[colg]; bhz = bh[HDIM + colg]; bhn = bh[2 * HDIM + colg];
        gi_b = gi16 + (size_t)fb * S * G3;
        flen = len[fb];
    }
    int Lg = 0;
    #pragma unroll
    for (int i = 0; i < PG; ++i) Lg = max(Lg, len[g * PG + i]);

    unsigned short* hb0 = h0f + (size_t)g * PG * HDIM;
    unsigned short* hb1 = h1f + (size_t)g * PG * HDIM;

    // gather chunks: c = tid, tid+256 -> pat = c&7, k8 = c>>3
    const int g0p = tid & 7,         g0k = tid >> 3;
    const int g1p = g0p,             g1k = g0k + 32;

    // ---- Gi(0) prologue prefetch
    float gr = 0.f, gz = 0.f, gn = 0.f;
    if (tid < 128) {
        gr = (float)__builtin_bit_cast(f16, gi_b[colg]);
        gz = (float)__builtin_bit_cast(f16, gi_b[HDIM + colg]);
        gn = (float)__builtin_bit_cast(f16, gi_b[2 * HDIM + colg]);
    }

    float lastH = 0.f;

    #pragma unroll 1
    for (int t = 0; t < Lg; ++t) {
        const unsigned short* src = (t & 1) ? hb1 : hb0;
        unsigned short*       dst = (t & 1) ? hb0 : hb1;

        // ---- gather h_t (published: guaranteed by previous iter's poll)
        {
            const unsigned short* p0 = src + g0p * HDIM + g0k * 8;
            const unsigned short* p1 = src + g1p * HDIM + g1k * 8;
            if (l2m) {
                u32x4 v0, v1;
                asm volatile(
                    "global_load_dwordx4 %0, %2, off sc0\n\t"
                    "global_load_dwordx4 %1, %3, off sc0\n\t"
                    "s_waitcnt vmcnt(0)"
                    : "=v"(v0), "=v"(v1) : "v"(p0), "v"(p1) : "memory");
                *(u32x4*)&hsb[g0k][g0p][0] = v0;
                *(u32x4*)&hsb[g1k][g1p][0] = v1;
            } else {
                u32x4 v0, v1;
                #pragma unroll
                for (int i = 0; i < 4; ++i) {
                    v0[i] = __hip_atomic_load((const unsigned int*)p0 + i,
                                              __ATOMIC_RELAXED, __HIP_MEMORY_SCOPE_AGENT);
                    v1[i] = __hip_atomic_load((const unsigned int*)p1 + i,
                                              __ATOMIC_RELAXED, __HIP_MEMORY_SCOPE_AGENT);
                }
                *(u32x4*)&hsb[g0k][g0p][0] = v0;
                *(u32x4*)&hsb[g1k][g1p][0] = v1;
            }
        }
        __syncthreads();                                   // B1

        // ---- MFMA: wave wv = gate wv; 2x8 independent K-chains
        // (af was loaded in the previous iteration's tail -- already in regs)
        if (wv < 3) {
            f32x4 a0 = (f32x4){0.f, 0.f, 0.f, 0.f};
            f32x4 a1 = (f32x4){0.f, 0.f, 0.f, 0.f};
            #pragma unroll
            for (int ks = 0; ks < 8; ++ks) {
                f32x4 bv = *(const f32x4*)&hsb[ks * 4 + (ln >> 4)][ln & 15][0];
                a0 = __builtin_amdgcn_mfma_f32_16x16x32_f16(
                    __builtin_bit_cast(f16x8, af[ks]),
                    __builtin_bit_cast(f16x8, bv), a0, 0, 0, 0);
            }
            #pragma unroll
            for (int ks = 8; ks < 16; ++ks) {
                f32x4 bv = *(const f32x4*)&hsb[ks * 4 + (ln >> 4)][ln & 15][0];
                a1 = __builtin_amdgcn_mfma_f32_16x16x32_f16(
                    __builtin_bit_cast(f16x8, af[ks]),
                    __builtin_bit_cast(f16x8, bv), a1, 0, 0, 0);
            }
            #pragma unroll
            for (int i = 0; i < 4; ++i)
                ghl[wv][(ln >> 4) * 4 + i][ln & 15] = a0[i] + a1[i];
        }
        __syncthreads();                                   // B2

        // ---- gates + LDS staging (tid<128)
        if (tid < 128) {
            float sr = ghl[0][hc][pat], sz = ghl[1][hc][pat], sn = ghl[2][hc][pat];
            float r  = 1.f / (1.f + expf(-(gr + sr + bhr)));
            float z  = 1.f / (1.f + expf(-(gz + sz + bhz)));
            float nn = tanhf(gn + r * (sn + bhn));
            float hold = (float)hsb[colg >> 3][pat][colg & 7];
            float hnew = (t < flen) ? ((1.f - z) * nn + z * hold) : hold;
            lastH = hnew;
            hst[pat][hc] = (f16)hnew;
        }
        __syncthreads();                                   // B_tail

        // ---- coalesced h store (wave 0: 64 dword stores), drain, flag
        if (tid < 64) {
            int sp = tid >> 3, dw = tid & 7;
            unsigned int v = *(const unsigned int*)&hst[sp][dw * 2];
            unsigned short* d = dst + sp * HDIM + c0 + dw * 2;
            if (l2m) {
                asm volatile("global_store_dword %0, %1, off sc0"
                             :: "v"(d), "v"(v) : "memory");
            } else {
                __hip_atomic_store((unsigned int*)d, v,
                                   __ATOMIC_RELAXED, __HIP_MEMORY_SCOPE_AGENT);
            }
        }
        asm volatile("s_waitcnt vmcnt(0)" ::: "memory");
        if (tid == 0) st_u32c(gflags + slice * 64, (unsigned)(t + 1), l2m);

        // ---- PIPELINED af reload for t+1: issued after the flag (cannot
        // delay the group), drains at B3 (overlaps the poll).  Opaque
        // pointer pin prevents CSE/hoist; values are constant -> correct.
        if (wv < 3) {
            asm volatile("" : "+v"(wrow));
            #pragma unroll
            for (int ks = 0; ks < 16; ++ks)
                af[ks] = *(const f32x4*)(wrow + ks * 32);
        }

        // ---- Gi(t+1) prefetch (overlaps the poll)
        float nr = 0.f, nz = 0.f, nn2 = 0.f;
        if (tid < 128) {
            int tn = (t + 1 < S) ? (t + 1) : (S - 1);
            const unsigned short* gp = gi_b + (size_t)tn * G3;
            nr  = (float)__builtin_bit_cast(f16, gp[colg]);
            nz  = (float)__builtin_bit_cast(f16, gp[HDIM + colg]);
            nn2 = (float)__builtin_bit_cast(f16, gp[2 * HDIM + colg]);
        }

        // ---- parallel poll for all peers at step t+1
        if (tid < NJ) {
            unsigned int* f = gflags + tid * 64;
            while (ld_u32c(f, l2m) < (unsigned)(t + 1))
                __builtin_amdgcn_s_sleep(1);
        }
        __syncthreads();                                   // B3

        gr = nr; gz = nz; gn = nn2;
    }

    // ---- final h -> hout (each (pat,col) has one owner thread)
    if (tid < 128)
        hout[(size_t)fb * HDIM + colg] = __builtin_bit_cast(unsigned short, (f16)lastH);
}

// ---------------------------------------------------------------------------
// K5: out[rank[b]] = tanh(W_lat @ h[b] + b_lat), h f16.
__global__ __launch_bounds__(128) void final_kernel(const unsigned short* __restrict__ h,
                                                    const float* __restrict__ Wl,
                                                    const float* __restrict__ bl,
                                                    const int* __restrict__ rank,
                                                    float* __restrict__ out) {
    int b = blockIdx.x;
    int l = threadIdx.x;
    __shared__ float hsh[HDIM];
    for (int i = l; i < HDIM; i += LDIM)
        hsh[i] = (float)__builtin_bit_cast(f16, h[(size_t)b * HDIM + i]);
    __syncthreads();
    float acc = bl[l];
    for (int k = 0; k < HDIM; ++k) acc += hsh[k] * Wl[(size_t)l * HDIM + k];
    out[(size_t)rank[b] * LDIM + l] = tanhf(acc);
}

// ---------------------------------------------------------------------------
extern "C" void kernel_launch(void* const* d_in, const int* in_sizes, int n_in,
                              void* d_out, int out_size, void* d_ws, size_t ws_size,
                              hipStream_t stream) {
    const int*   seq = (const int*)d_in[0];
    const int*   len = (const int*)d_in[1];
    const float* Ew  = (const float*)d_in[2];
    const float* Wi  = (const float*)d_in[3];
    const float* Wh  = (const float*)d_in[4];
    const float* bi  = (const float*)d_in[5];
    const float* bh  = (const float*)d_in[6];
    const float* Wl  = (const float*)d_in[7];
    const float* bl  = (const float*)d_in[8];
    float* out = (float*)d_out;

    unsigned short* ws16 = (unsigned short*)d_ws;
    unsigned short* emb16 = ws16;                               // B*S*E
    unsigned short* gi16  = emb16 + (size_t)B * S * EDIM;       // B*S*3H
    unsigned short* wi16  = gi16 + (size_t)B * S * G3;          // 3H*E
    unsigned short* wh16  = wi16 + (size_t)G3 * EDIM;           // 3H*H
    unsigned short* h0f   = wh16 + (size_t)G3 * HDIM;           // B*H
    unsigned short* h1f   = h0f + (size_t)B * HDIM;             // B*H
    unsigned short* hout  = h1f + (size_t)B * HDIM;             // B*H
    int*   rank = (int*)(hout + (size_t)B * HDIM);              // B
    unsigned int* sync = (unsigned int*)(rank + B);             // SYNC_TOTAL

    emb_kernel<<<B * S, 256, 0, stream>>>(seq, Ew, emb16);
    init_kernel<<<128, 256, 0, stream>>>(len, Wi, Wh, rank, sync,
                                         (unsigned int*)h0f, wi16, wh16);
    gi_gemm16<<<dim3(B * S / 64, G3 / 64), 256, 0, stream>>>(wi16, emb16, bi, gi16);

    gru_persist<<<dim3(NG, NJ), 256, 0, stream>>>(gi16, wh16, bh, len,
                                                  h0f, h1f, hout, sync);
    final_kernel<<<B, LDIM, 0, stream>>>(hout, Wl, bl, rank, out);
}

// Round 16
// 279.544 us; speedup vs baseline: 1.2977x; 1.2977x over previous
//
#include <hip/hip_runtime.h>
#include <cmath>

typedef _Float16 f16;
typedef _Float16 f16x8 __attribute__((ext_vector_type(8)));
typedef float f32x4 __attribute__((ext_vector_type(4)));
typedef unsigned int u32x4 __attribute__((ext_vector_type(4)));

#define B 64
#define S 80
#define KC 32
#define EDIM 256
#define HDIM 512
#define G3 1536
#define LDIM 128

// persistent-GRU geometry (R11 core — measured optimum: 205us gru, 280 total)
#define NG 8     // groups (grid(8,32): linear%8 == g -> one XCD per group)
#define PG 8     // patients per group
#define NJ 32    // blocks per group
#define CPB 16   // h-cols per block

// sync area layout (u32 units)
#define OFF_PCNT  (NG * NJ * 64)
#define OFF_XCD   (OFF_PCNT + NG * 64)
#define OFF_TEST  (OFF_XCD + NG * NJ)
#define OFF_FAIL  (OFF_TEST + NG * NJ * 64)
#define SYNC_TOTAL (OFF_FAIL + NG)

// ---------------------------------------------------------------------------
__device__ __forceinline__ unsigned int ld_u32c(const unsigned int* p, bool l2) {
    unsigned int v;
    if (l2) {
        asm volatile("global_load_dword %0, %1, off sc0\n\ts_waitcnt vmcnt(0)"
                     : "=v"(v) : "v"(p) : "memory");
    } else {
        v = __hip_atomic_load(p, __ATOMIC_RELAXED, __HIP_MEMORY_SCOPE_AGENT);
    }
    return v;
}
__device__ __forceinline__ void st_u32c(unsigned int* p, unsigned int v, bool l2) {
    if (l2) {
        asm volatile("global_store_dword %0, %1, off sc0" :: "v"(p), "v"(v) : "memory");
    } else {
        __hip_atomic_store(p, v, __ATOMIC_RELAXED, __HIP_MEMORY_SCOPE_AGENT);
    }
}

// ---------------------------------------------------------------------------
// K1: multi-hot embedding + tanh -> f16.
__global__ __launch_bounds__(256) void emb_kernel(const int* __restrict__ seq,
                                                  const float* __restrict__ Ew,
                                                  unsigned short* __restrict__ emb16) {
    int bs = blockIdx.x;
    __shared__ int codes[KC];
    __shared__ int valid[KC];
    int tid = threadIdx.x;
    if (tid < KC) codes[tid] = seq[bs * KC + tid];
    __syncthreads();
    if (tid < KC) {
        int c = codes[tid];
        int v = (c != 0);
        for (int i = 0; i < tid; ++i)
            if (codes[i] == c) v = 0;
        valid[tid] = v;
    }
    __syncthreads();
    float acc = 0.f;
    for (int j = 0; j < KC; ++j) {
        if (valid[j]) acc += Ew[codes[j] * EDIM + tid];
    }
    emb16[bs * EDIM + tid] = __builtin_bit_cast(unsigned short, (f16)tanhf(acc));
}

// ---------------------------------------------------------------------------
// K2: Gi16 = emb16 @ Wi16^T + bi via MFMA f16 (verified).
__global__ __launch_bounds__(256) void gi_gemm16(
        const unsigned short* __restrict__ wi16,
        const unsigned short* __restrict__ emb16,
        const float* __restrict__ bi,
        unsigned short* __restrict__ gi16) {
    __shared__ __align__(16) f16 At[64][256];
    __shared__ __align__(16) f16 Bt[64][256];
    const int m0 = blockIdx.x * 64;   // visits
    const int n0 = blockIdx.y * 64;   // gates
    const int tid = threadIdx.x;
    #pragma unroll
    for (int i = 0; i < 8; ++i) {
        int ci = tid + i * 256;
        int row = ci >> 5, c = ci & 31;
        int sc = c ^ (row & 7);
        *(f32x4*)&At[row][sc * 8] =
            *(const f32x4*)(wi16 + (size_t)(n0 + row) * EDIM + c * 8);
        *(f32x4*)&Bt[row][sc * 8] =
            *(const f32x4*)(emb16 + (size_t)(m0 + row) * EDIM + c * 8);
    }
    __syncthreads();
    const int wv = tid >> 6, ln = tid & 63;
    const int lr = ln & 15, hi = ln >> 4;
    const int arow = wv * 16 + lr;
    f32x4 acc[4] = {};
    #pragma unroll
    for (int ks = 0; ks < 8; ++ks) {
        int ca = (ks * 4 + hi) ^ (arow & 7);
        f32x4 av = *(const f32x4*)&At[arow][ca * 8];
        #pragma unroll
        for (int vt = 0; vt < 4; ++vt) {
            int brow = vt * 16 + lr;
            int cb = (ks * 4 + hi) ^ (brow & 7);
            f32x4 bv = *(const f32x4*)&Bt[brow][cb * 8];
            acc[vt] = __builtin_amdgcn_mfma_f32_16x16x32_f16(
                __builtin_bit_cast(f16x8, av), __builtin_bit_cast(f16x8, bv),
                acc[vt], 0, 0, 0);
        }
    }
    const int gate0 = n0 + wv * 16 + hi * 4;
    float4 bv4 = *(const float4*)(bi + gate0);
    #pragma unroll
    for (int vt = 0; vt < 4; ++vt) {
        int vis = m0 + vt * 16 + lr;
        union { unsigned short u[4]; unsigned long long ll; } pk;
        pk.u[0] = __builtin_bit_cast(unsigned short, (f16)(acc[vt][0] + bv4.x));
        pk.u[1] = __builtin_bit_cast(unsigned short, (f16)(acc[vt][1] + bv4.y));
        pk.u[2] = __builtin_bit_cast(unsigned short, (f16)(acc[vt][2] + bv4.z));
        pk.u[3] = __builtin_bit_cast(unsigned short, (f16)(acc[vt][3] + bv4.w));
        *(unsigned long long*)(gi16 + (size_t)vis * G3 + gate0) = pk.ll;
    }
}

// ---------------------------------------------------------------------------
// K3: init — zero h buffers + sync, convert Wi/Wh -> f16, rank.
__global__ __launch_bounds__(256) void init_kernel(const int* __restrict__ len,
                                                   const float* __restrict__ Wi,
                                                   const float* __restrict__ Wh,
                                                   int* __restrict__ rank,
                                                   unsigned int* __restrict__ sync,
                                                   unsigned int* __restrict__ hz,
                                                   unsigned short* __restrict__ wi16,
                                                   unsigned short* __restrict__ wh16) {
    int idx = blockIdx.x * 256 + threadIdx.x;       // 128*256 = 32768
    if (idx < 16384) { hz[idx] = 0u; hz[16384 + idx] = 0u; }   // h0f+h1f
    for (int o = idx; o < SYNC_TOTAL; o += 32768) sync[o] = 0u;
    for (int o = idx; o < G3 * EDIM; o += 32768)
        wi16[o] = __builtin_bit_cast(unsigned short, (f16)Wi[o]);
    for (int o = idx; o < G3 * HDIM; o += 32768)
        wh16[o] = __builtin_bit_cast(unsigned short, (f16)Wh[o]);
    if (blockIdx.x == 0 && threadIdx.x < B) {
        int t = threadIdx.x;
        int lb = len[t];
        int r = 0;
        for (int i = 0; i < B; ++i) {
            int li = len[i];
            r += (li > lb) || (li == lb && i < t);
        }
        rank[t] = r;
    }
}

// ---------------------------------------------------------------------------
// K4: persistent MFMA GRU — R11 measured optimum, restored byte-for-byte.
// Thin blocks (32/group), af remat-from-L2 inside the MFMA phase (all
// residency schemes regressed: R12 LDS-weights +42us, R13 in-wave gates
// +60, R14 tail-collapse +28, R15 pipelined reload +85), 4-barrier step,
// flag-publish -> Gi-prefetch -> poll ordering.  sc0/XCD-L2 when probed
// OK, L3 relaxed-agent fallback.
__global__ __launch_bounds__(256, 1) void gru_persist(
        const unsigned short* __restrict__ gi16,
        const unsigned short* __restrict__ wh16,
        const float* __restrict__ bh, const int* __restrict__ len,
        unsigned short* __restrict__ h0f, unsigned short* __restrict__ h1f,
        unsigned short* __restrict__ hout,
        unsigned int* __restrict__ sync) {
    const int g     = blockIdx.x;          // 0..NG-1
    const int slice = blockIdx.y;          // 0..NJ-1
    const int tid   = threadIdx.x;
    const int wv    = tid >> 6;
    const int ln    = tid & 63;
    const int c0    = slice * CPB;

    __shared__ __align__(16) f16 hsb[64][16][8];   // [k8][pat(8+8 pad)][8]
    __shared__ float ghl[3][16][16];
    __shared__ f16 hst[PG][CPB];                   // h-store staging
    __shared__ unsigned int ids_sh[NJ];
    __shared__ unsigned int fail_sh;

    // zero pad-patient rows once (stay zero)
    for (int c = tid; c < 64 * 8; c += 256)
        *(float4*)&hsb[c >> 3][8 + (c & 7)][0] = make_float4(0.f, 0.f, 0.f, 0.f);

    // ---- A-operand (Wh f16 slice) per wave (wv<3)
    f32x4 af[16];
    if (wv < 3) {
        const unsigned short* wrow =
            wh16 + (size_t)(wv * HDIM + c0 + (ln & 15)) * HDIM + (ln >> 4) * 8;
        #pragma unroll
        for (int ks = 0; ks < 16; ++ks)
            af[ks] = *(const f32x4*)(wrow + ks * 32);
    } else {
        #pragma unroll
        for (int ks = 0; ks < 16; ++ks) af[ks] = (f32x4){0.f, 0.f, 0.f, 0.f};
    }
    #pragma unroll
    for (int ks = 0; ks < 16; ++ks) asm volatile("" : "+v"(af[ks]));

    // ---- sync pointers
    unsigned int* gflags = sync + (size_t)(g * NJ) * 64;
    unsigned int* pcnt   = sync + OFF_PCNT + g * 64;
    unsigned int* xcdrow = sync + OFF_XCD + g * NJ;
    unsigned int* town   = sync + OFF_TEST + (g * NJ + slice) * 64;
    unsigned int* tpeer  = sync + OFF_TEST + (g * NJ + ((slice + 1) & (NJ - 1))) * 64;
    unsigned int* failw  = sync + OFF_FAIL + g;

    auto l3bar = [&](unsigned int target) {
        if (tid == 0) {
            asm volatile("s_waitcnt vmcnt(0)" ::: "memory");
            __hip_atomic_fetch_add(pcnt, 1u, __ATOMIC_RELAXED, __HIP_MEMORY_SCOPE_AGENT);
            while (__hip_atomic_load(pcnt, __ATOMIC_RELAXED, __HIP_MEMORY_SCOPE_AGENT) < target)
                __builtin_amdgcn_s_sleep(1);
        }
        __syncthreads();
    };

    // ---- XCD identity + sc0 coherence probe (R6 recipe, proven)
    unsigned int myxcc;
    asm volatile("s_getreg_b32 %0, hwreg(HW_REG_XCC_ID)" : "=s"(myxcc));
    myxcc &= 0xFu;
    if (tid == 0)
        __hip_atomic_store(xcdrow + slice, myxcc, __ATOMIC_RELAXED, __HIP_MEMORY_SCOPE_AGENT);
    l3bar(NJ);
    if (tid < NJ)
        ids_sh[tid] = __hip_atomic_load(xcdrow + tid, __ATOMIC_RELAXED, __HIP_MEMORY_SCOPE_AGENT);
    __syncthreads();
    bool same_xcd = true;
    #pragma unroll
    for (int i = 1; i < NJ; ++i) same_xcd &= (ids_sh[i] == ids_sh[0]);

    bool l2m = false;
    if (same_xcd) {
        const unsigned int M1 = 0xA5A50000u + (unsigned)slice;
        const unsigned int M2 = 0x5A5A0000u + (unsigned)slice;
        const unsigned int P1 = 0xA5A50000u + (unsigned)((slice + 1) & (NJ - 1));
        const unsigned int P2 = 0x5A5A0000u + (unsigned)((slice + 1) & (NJ - 1));
        unsigned int r1 = 0, r2 = 0;
        if (tid == 0) st_u32c(town, M1, true);
        l3bar(2 * NJ);
        if (tid == 0) r1 = ld_u32c(tpeer, true);
        l3bar(3 * NJ);
        if (tid == 0) st_u32c(town, M2, true);
        l3bar(4 * NJ);
        if (tid == 0) {
            r2 = ld_u32c(tpeer, true);
            if (r1 != P1 || r2 != P2)
                __hip_atomic_fetch_or(failw, 1u, __ATOMIC_RELAXED, __HIP_MEMORY_SCOPE_AGENT);
        }
        l3bar(5 * NJ);
        if (tid == 0)
            fail_sh = __hip_atomic_load(failw, __ATOMIC_RELAXED, __HIP_MEMORY_SCOPE_AGENT);
        __syncthreads();
        l2m = (fail_sh == 0u);
    }

    // ---- per-thread statics (tid<128: one (pat, col) each)
    const int pat  = tid & 7;
    const int hc   = tid >> 3;
    const int colg = c0 + hc;
    const int fb   = g * PG + pat;
    float bhr = 0.f, bhz = 0.f, bhn = 0.f;
    const unsigned short* gi_b = gi16;
    int flen = 0;
    if (tid < 128) {
        bhr = bh[colg]; bhz = bh[HDIM + colg]; bhn = bh[2 * HDIM + colg];
        gi_b = gi16 + (size_t)fb * S * G3;
        flen = len[fb];
    }
    int Lg = 0;
    #pragma unroll
    for (int i = 0; i < PG; ++i) Lg = max(Lg, len[g * PG + i]);

    unsigned short* hb0 = h0f + (size_t)g * PG * HDIM;
    unsigned short* hb1 = h1f + (size_t)g * PG * HDIM;

    // gather chunks: c = tid, tid+256 -> pat = c&7, k8 = c>>3
    const int g0p = tid & 7,         g0k = tid >> 3;
    const int g1p = g0p,             g1k = g0k + 32;

    // ---- Gi(0) prologue prefetch
    float gr = 0.f, gz = 0.f, gn = 0.f;
    if (tid < 128) {
        gr = (float)__builtin_bit_cast(f16, gi_b[colg]);
        gz = (float)__builtin_bit_cast(f16, gi_b[HDIM + colg]);
        gn = (float)__builtin_bit_cast(f16, gi_b[2 * HDIM + colg]);
    }

    float lastH = 0.f;

    #pragma unroll 1
    for (int t = 0; t < Lg; ++t) {
        const unsigned short* src = (t & 1) ? hb1 : hb0;
        unsigned short*       dst = (t & 1) ? hb0 : hb1;

        // ---- gather h_t (published: guaranteed by previous iter's poll)
        {
            const unsigned short* p0 = src + g0p * HDIM + g0k * 8;
            const unsigned short* p1 = src + g1p * HDIM + g1k * 8;
            if (l2m) {
                u32x4 v0, v1;
                asm volatile(
                    "global_load_dwordx4 %0, %2, off sc0\n\t"
                    "global_load_dwordx4 %1, %3, off sc0\n\t"
                    "s_waitcnt vmcnt(0)"
                    : "=v"(v0), "=v"(v1) : "v"(p0), "v"(p1) : "memory");
                *(u32x4*)&hsb[g0k][g0p][0] = v0;
                *(u32x4*)&hsb[g1k][g1p][0] = v1;
            } else {
                u32x4 v0, v1;
                #pragma unroll
                for (int i = 0; i < 4; ++i) {
                    v0[i] = __hip_atomic_load((const unsigned int*)p0 + i,
                                              __ATOMIC_RELAXED, __HIP_MEMORY_SCOPE_AGENT);
                    v1[i] = __hip_atomic_load((const unsigned int*)p1 + i,
                                              __ATOMIC_RELAXED, __HIP_MEMORY_SCOPE_AGENT);
                }
                *(u32x4*)&hsb[g0k][g0p][0] = v0;
                *(u32x4*)&hsb[g1k][g1p][0] = v1;
            }
        }
        __syncthreads();

        // ---- MFMA: wave wv = gate wv; 2x8 independent K-chains
        if (wv < 3) {
            f32x4 a0 = (f32x4){0.f, 0.f, 0.f, 0.f};
            f32x4 a1 = (f32x4){0.f, 0.f, 0.f, 0.f};
            #pragma unroll
            for (int ks = 0; ks < 8; ++ks) {
                f32x4 bv = *(const f32x4*)&hsb[ks * 4 + (ln >> 4)][ln & 15][0];
                a0 = __builtin_amdgcn_mfma_f32_16x16x32_f16(
                    __builtin_bit_cast(f16x8, af[ks]),
                    __builtin_bit_cast(f16x8, bv), a0, 0, 0, 0);
            }
            #pragma unroll
            for (int ks = 8; ks < 16; ++ks) {
                f32x4 bv = *(const f32x4*)&hsb[ks * 4 + (ln >> 4)][ln & 15][0];
                a1 = __builtin_amdgcn_mfma_f32_16x16x32_f16(
                    __builtin_bit_cast(f16x8, af[ks]),
                    __builtin_bit_cast(f16x8, bv), a1, 0, 0, 0);
            }
            #pragma unroll
            for (int i = 0; i < 4; ++i)
                ghl[wv][(ln >> 4) * 4 + i][ln & 15] = a0[i] + a1[i];
        }
        __syncthreads();

        // ---- gates + LDS staging (tid<128)
        if (tid < 128) {
            float sr = ghl[0][hc][pat], sz = ghl[1][hc][pat], sn = ghl[2][hc][pat];
            float r  = 1.f / (1.f + expf(-(gr + sr + bhr)));
            float z  = 1.f / (1.f + expf(-(gz + sz + bhz)));
            float nn = tanhf(gn + r * (sn + bhn));
            float hold = (float)hsb[colg >> 3][pat][colg & 7];
            float hnew = (t < flen) ? ((1.f - z) * nn + z * hold) : hold;
            lastH = hnew;
            hst[pat][hc] = (f16)hnew;
        }
        __syncthreads();

        // ---- coalesced h store (wave 0: 64 dword stores), drain, flag
        if (tid < 64) {
            int sp = tid >> 3, dw = tid & 7;
            unsigned int v = *(const unsigned int*)&hst[sp][dw * 2];
            unsigned short* d = dst + sp * HDIM + c0 + dw * 2;
            if (l2m) {
                asm volatile("global_store_dword %0, %1, off sc0"
                             :: "v"(d), "v"(v) : "memory");
            } else {
                __hip_atomic_store((unsigned int*)d, v,
                                   __ATOMIC_RELAXED, __HIP_MEMORY_SCOPE_AGENT);
            }
        }
        asm volatile("s_waitcnt vmcnt(0)" ::: "memory");
        if (tid == 0) st_u32c(gflags + slice * 64, (unsigned)(t + 1), l2m);

        // ---- Gi(t+1) prefetch AFTER flag publish: latency overlaps the poll
        float nr = 0.f, nz = 0.f, nn2 = 0.f;
        if (tid < 128) {
            int tn = (t + 1 < S) ? (t + 1) : (S - 1);
            const unsigned short* gp = gi_b + (size_t)tn * G3;
            nr  = (float)__builtin_bit_cast(f16, gp[colg]);
            nz  = (float)__builtin_bit_cast(f16, gp[HDIM + colg]);
            nn2 = (float)__builtin_bit_cast(f16, gp[2 * HDIM + colg]);
        }

        // ---- parallel poll for all peers at step t+1
        if (tid < NJ) {
            unsigned int* f = gflags + tid * 64;
            while (ld_u32c(f, l2m) < (unsigned)(t + 1))
                __builtin_amdgcn_s_sleep(1);
        }
        __syncthreads();

        gr = nr; gz = nz; gn = nn2;
    }

    // ---- final h -> hout (each (pat,col) has one owner thread)
    if (tid < 128)
        hout[(size_t)fb * HDIM + colg] = __builtin_bit_cast(unsigned short, (f16)lastH);
}

// ---------------------------------------------------------------------------
// K5: out[rank[b]] = tanh(W_lat @ h[b] + b_lat), h f16.
__global__ __launch_bounds__(128) void final_kernel(const unsigned short* __restrict__ h,
                                                    const float* __restrict__ Wl,
                                                    const float* __restrict__ bl,
                                                    const int* __restrict__ rank,
                                                    float* __restrict__ out) {
    int b = blockIdx.x;
    int l = threadIdx.x;
    __shared__ float hsh[HDIM];
    for (int i = l; i < HDIM; i += LDIM)
        hsh[i] = (float)__builtin_bit_cast(f16, h[(size_t)b * HDIM + i]);
    __syncthreads();
    float acc = bl[l];
    for (int k = 0; k < HDIM; ++k) acc += hsh[k] * Wl[(size_t)l * HDIM + k];
    out[(size_t)rank[b] * LDIM + l] = tanhf(acc);
}

// ---------------------------------------------------------------------------
extern "C" void kernel_launch(void* const* d_in, const int* in_sizes, int n_in,
                              void* d_out, int out_size, void* d_ws, size_t ws_size,
                              hipStream_t stream) {
    const int*   seq = (const int*)d_in[0];
    const int*   len = (const int*)d_in[1];
    const float* Ew  = (const float*)d_in[2];
    const float* Wi  = (const float*)d_in[3];
    const float* Wh  = (const float*)d_in[4];
    const float* bi  = (const float*)d_in[5];
    const float* bh  = (const float*)d_in[6];
    const float* Wl  = (const float*)d_in[7];
    const float* bl  = (const float*)d_in[8];
    float* out = (float*)d_out;

    unsigned short* ws16 = (unsigned short*)d_ws;
    unsigned short* emb16 = ws16;                               // B*S*E
    unsigned short* gi16  = emb16 + (size_t)B * S * EDIM;       // B*S*3H
    unsigned short* wi16  = gi16 + (size_t)B * S * G3;          // 3H*E
    unsigned short* wh16  = wi16 + (size_t)G3 * EDIM;           // 3H*H
    unsigned short* h0f   = wh16 + (size_t)G3 * HDIM;           // B*H
    unsigned short* h1f   = h0f + (size_t)B * HDIM;             // B*H
    unsigned short* hout  = h1f + (size_t)B * HDIM;             // B*H
    int*   rank = (int*)(hout + (size_t)B * HDIM);              // B
    unsigned int* sync = (unsigned int*)(rank + B);             // SYNC_TOTAL

    emb_kernel<<<B * S, 256, 0, stream>>>(seq, Ew, emb16);
    init_kernel<<<128, 256, 0, stream>>>(len, Wi, Wh, rank, sync,
                                         (unsigned int*)h0f, wi16, wh16);
    gi_gemm16<<<dim3(B * S / 64, G3 / 64), 256, 0, stream>>>(wi16, emb16, bi, gi16);

    gru_persist<<<dim3(NG, NJ), 256, 0, stream>>>(gi16, wh16, bh, len,
                                                  h0f, h1f, hout, sync);
    final_kernel<<<B, LDIM, 0, stream>>>(hout, Wl, bl, rank, out);
}